// Round 1
// baseline (295.800 us; speedup 1.0000x reference)
//
#include <hip/hip_runtime.h>
#include <math.h>

// Problem constants: B=4, N=256, C=512, H=8, Dh=64
#define BB 4
#define NN 256
#define CC 512
#define HH 8
#define DH 64

// ---------------------------------------------------------------------------
// GEMM: C[M,N] = A[M,K] * B[N,K]^T  (+ optional bias[N])
// Both A and B are row-major with contiguous K (dot-of-rows) — matches both
// the qkv projection (x @ w_qkv^T) and the output projection.
// BM=64, BN=64, BK=16, 128 threads, 4x8 microtile per thread.
// ---------------------------------------------------------------------------
template <bool BIAS>
__global__ __launch_bounds__(128, 4) void gemm_tn(
    const float* __restrict__ A, const float* __restrict__ B,
    const float* __restrict__ bias, float* __restrict__ C, int M, int N,
    int K) {
  __shared__ float As[16][64];  // As[k][m]
  __shared__ float Bs[16][64];  // Bs[k][n]
  const int t = threadIdx.x;
  const int bm = blockIdx.y * 64;
  const int bn = blockIdx.x * 64;
  const int tm = t & 15;  // m0 = 4*tm
  const int tn = t >> 4;  // n0 = 8*tn

  float acc[4][8];
#pragma unroll
  for (int i = 0; i < 4; i++)
#pragma unroll
    for (int j = 0; j < 8; j++) acc[i][j] = 0.f;

  for (int k0 = 0; k0 < K; k0 += 16) {
#pragma unroll
    for (int i = 0; i < 2; i++) {
      int u = t + 128 * i;       // 0..255 float4 slots (64 rows x 4)
      int row = u >> 2;          // 0..63
      int c4 = (u & 3) << 2;     // 0,4,8,12
      float4 av = *(const float4*)(A + (size_t)(bm + row) * K + k0 + c4);
      float4 bv = *(const float4*)(B + (size_t)(bn + row) * K + k0 + c4);
      As[c4 + 0][row] = av.x;
      As[c4 + 1][row] = av.y;
      As[c4 + 2][row] = av.z;
      As[c4 + 3][row] = av.w;
      Bs[c4 + 0][row] = bv.x;
      Bs[c4 + 1][row] = bv.y;
      Bs[c4 + 2][row] = bv.z;
      Bs[c4 + 3][row] = bv.w;
    }
    __syncthreads();
#pragma unroll
    for (int k = 0; k < 16; k++) {
      float4 a = *(const float4*)&As[k][4 * tm];
      float4 b0 = *(const float4*)&Bs[k][8 * tn];
      float4 b1 = *(const float4*)&Bs[k][8 * tn + 4];
      float am[4] = {a.x, a.y, a.z, a.w};
      float bv[8] = {b0.x, b0.y, b0.z, b0.w, b1.x, b1.y, b1.z, b1.w};
#pragma unroll
      for (int i = 0; i < 4; i++)
#pragma unroll
        for (int j = 0; j < 8; j++) acc[i][j] = fmaf(am[i], bv[j], acc[i][j]);
    }
    __syncthreads();
  }

#pragma unroll
  for (int i = 0; i < 4; i++) {
    int m = bm + 4 * tm + i;
#pragma unroll
    for (int j = 0; j < 8; j += 4) {
      float4 v;
      v.x = acc[i][j + 0];
      v.y = acc[i][j + 1];
      v.z = acc[i][j + 2];
      v.w = acc[i][j + 3];
      if (BIAS) {
        int n = bn + 8 * tn + j;
        v.x += bias[n + 0];
        v.y += bias[n + 1];
        v.z += bias[n + 2];
        v.w += bias[n + 3];
      }
      *(float4*)(C + (size_t)m * N + bn + 8 * tn + j) = v;
    }
  }
}

// ---------------------------------------------------------------------------
// Fused Fourier attention.
// qkv layout (from gemm): row (b*N+n) of 3*C floats; q at [h*64], k at
// [512+h*64], v at [1024+h*64].
// Grid: (16 query-chunks, H, B); block 256 threads = 4 waves.
// Each wave handles 4 queries; keys processed in 4 tiles of 64.
// Score phase: lane = key (1 key/lane), K read from transposed LDS tile
// (conflict-free). num/den product trick: one division per (q,k) pair.
// AV phase: lane = dim; a4 handed over through per-wave LDS slice
// (same-wave write->read, compiler inserts lgkmcnt wait; no barrier needed).
// ---------------------------------------------------------------------------
__global__ __launch_bounds__(256, 2) void fourier_attn(
    const float* __restrict__ qkv, const float* __restrict__ paramR,
    float* __restrict__ out /* (B*N, C), head-major channels */) {
  __shared__ float KT[DH][65];      // KT[d][j] (transposed key tile, padded)
  __shared__ float Vt[64][DH];      // Vt[j][d]
  __shared__ float A4[4][64][4];    // [wave][key j][query q]

  const int t = threadIdx.x;
  const int lane = t & 63;
  const int wv = t >> 6;
  const int qc = blockIdx.x;  // 0..15 (chunk of 16 queries)
  const int h = blockIdx.y;
  const int b = blockIdx.z;
  const float R = paramR[0];

  const float* base = qkv + (size_t)b * NN * (3 * CC) + h * DH;
  const int q0 = qc * 16 + wv * 4;

  float Sp[4] = {0.f, 0.f, 0.f, 0.f};   // per-lane partial sum of a4
  float acc[4] = {0.f, 0.f, 0.f, 0.f};  // per-lane (=dim) AV accumulator

  for (int jt = 0; jt < 4; jt++) {
    __syncthreads();  // protect LDS tiles from previous iteration's readers
    // ---- stage K (transposed) and V tiles: rows jt*64 .. jt*64+63
#pragma unroll
    for (int u0 = 0; u0 < 4; u0++) {
      int u = t + 256 * u0;     // 0..1023 float4 slots (64 rows x 16)
      int r = u >> 4;           // key row 0..63
      int c4 = (u & 15) << 2;   // dim 0..60
      const float* krow = base + (size_t)(jt * 64 + r) * (3 * CC) + CC;
      float4 kv = *(const float4*)(krow + c4);
      KT[c4 + 0][r] = kv.x;
      KT[c4 + 1][r] = kv.y;
      KT[c4 + 2][r] = kv.z;
      KT[c4 + 3][r] = kv.w;
      const float* vrow = base + (size_t)(jt * 64 + r) * (3 * CC) + 2 * CC;
      *(float4*)&Vt[r][c4] = *(const float4*)(vrow + c4);
    }
    __syncthreads();

    // ---- score phase: lane = key j = jt*64 + lane
    float kreg[DH];
#pragma unroll
    for (int d = 0; d < DH; d++) kreg[d] = KT[d][lane];

#pragma unroll
    for (int q = 0; q < 4; q++) {
      const float* qrow = base + (size_t)(q0 + q) * (3 * CC);
      float num = 1.f, den = 1.f;
#pragma unroll
      for (int d4 = 0; d4 < 16; d4++) {
        float4 qv = *(const float4*)(qrow + 4 * d4);
        float qa[4] = {qv.x, qv.y, qv.z, qv.w};
#pragma unroll
        for (int j = 0; j < 4; j++) {
          float diff = qa[j] - kreg[4 * d4 + j];
          bool nr = fabsf(diff) < 1e-3f;  // sinc(Rd)≈R to 2e-7 rel here
          float sn = __sinf(R * diff);
          num *= nr ? R : sn;
          den *= nr ? 1.f : diff;
        }
      }
      float sc = num / den;
      float s2 = sc * sc;
      float a4 = s2 * s2;
      Sp[q] += a4;
      A4[wv][lane][q] = a4;
    }

    // ---- AV phase: lane = dim d; reads only this wave's A4 slice
#pragma unroll 8
    for (int j = 0; j < 64; j++) {
      float4 a4v = *(const float4*)&A4[wv][j][0];
      float vj = Vt[j][lane];
      acc[0] = fmaf(a4v.x, vj, acc[0]);
      acc[1] = fmaf(a4v.y, vj, acc[1]);
      acc[2] = fmaf(a4v.z, vj, acc[2]);
      acc[3] = fmaf(a4v.w, vj, acc[3]);
    }
  }

  // ---- finalize: reduce Sp across lanes, normalize, store
#pragma unroll
  for (int q = 0; q < 4; q++) {
    float s = Sp[q];
#pragma unroll
    for (int off = 32; off > 0; off >>= 1) s += __shfl_xor(s, off, 64);
    float o = acc[q] / (s + 1e-6f);
    out[(size_t)(b * NN + q0 + q) * CC + h * DH + lane] = o;
  }
}

// ---------------------------------------------------------------------------
extern "C" void kernel_launch(void* const* d_in, const int* in_sizes, int n_in,
                              void* d_out, int out_size, void* d_ws,
                              size_t ws_size, hipStream_t stream) {
  const float* x = (const float*)d_in[0];       // (B,N,C)
  const float* w_qkv = (const float*)d_in[1];   // (3C, C)
  const float* w_proj = (const float*)d_in[2];  // (C, C)
  const float* b_proj = (const float*)d_in[3];  // (C,)
  const float* paramR = (const float*)d_in[4];  // (1,)
  float* outp = (float*)d_out;                  // (B,N,C)

  float* qkv_ws = (float*)d_ws;                           // 1024*1536 floats
  float* attn_ws = qkv_ws + (size_t)BB * NN * 3 * CC;     // 1024*512 floats

  // 1) qkv = x @ w_qkv^T : M=1024, N=1536, K=512
  gemm_tn<false><<<dim3(3 * CC / 64, BB * NN / 64), 128, 0, stream>>>(
      x, w_qkv, nullptr, qkv_ws, BB * NN, 3 * CC, CC);

  // 2) fused fourier attention -> attn_ws (B*N, C)
  fourier_attn<<<dim3(NN / 16, HH, BB), 256, 0, stream>>>(qkv_ws, paramR,
                                                          attn_ws);

  // 3) out = attn_ws @ w_proj^T + b_proj : M=1024, N=512, K=512
  gemm_tn<true><<<dim3(CC / 64, BB * NN / 64), 128, 0, stream>>>(
      attn_ws, w_proj, b_proj, outp, BB * NN, CC, CC);
}

// Round 3
// 259.163 us; speedup vs baseline: 1.1414x; 1.1414x over previous
//
#include <hip/hip_runtime.h>
#include <math.h>

// Problem constants: B=4, N=256, C=512, H=8, Dh=64
#define BB 4
#define NN 256
#define CC 512
#define HH 8
#define DH 64

// ---------------------------------------------------------------------------
// Split-K GEMM: C[M,N] += A[M,K_chunk] * B[N,K_chunk]^T (+ bias on chunk 0)
// A,B row-major with contiguous K (dot-of-rows). C must be zeroed beforehand.
// BM=BN=64, BK=16, 256 threads (16x16), 4x4 microtile -> low VGPR, high waves.
// grid.z = number of K-splits; KS = K / gridDim.z elements per split.
// ---------------------------------------------------------------------------
template <bool BIAS>
__global__ __launch_bounds__(256, 4) void gemm_tn_splitk(
    const float* __restrict__ A, const float* __restrict__ B,
    const float* __restrict__ bias, float* __restrict__ C, int M, int N,
    int K, int KS) {
  __shared__ float As[16][64];  // As[k][m]
  __shared__ float Bs[16][64];  // Bs[k][n]
  const int t = threadIdx.x;
  const int bm = blockIdx.y * 64;
  const int bn = blockIdx.x * 64;
  const int ks = blockIdx.z;
  const int tm = t & 15;  // m0 = 4*tm
  const int tn = t >> 4;  // n0 = 4*tn

  float acc[4][4];
#pragma unroll
  for (int i = 0; i < 4; i++)
#pragma unroll
    for (int j = 0; j < 4; j++) acc[i][j] = 0.f;

  const int kbeg = ks * KS;
  const int kend = kbeg + KS;
  // staging map: 256 threads x 1 float4 = 64 rows x 16 k
  const int srow = t >> 2;       // 0..63
  const int sc4 = (t & 3) << 2;  // 0,4,8,12

  for (int k0 = kbeg; k0 < kend; k0 += 16) {
    float4 av = *(const float4*)(A + (size_t)(bm + srow) * K + k0 + sc4);
    float4 bv = *(const float4*)(B + (size_t)(bn + srow) * K + k0 + sc4);
    As[sc4 + 0][srow] = av.x;
    As[sc4 + 1][srow] = av.y;
    As[sc4 + 2][srow] = av.z;
    As[sc4 + 3][srow] = av.w;
    Bs[sc4 + 0][srow] = bv.x;
    Bs[sc4 + 1][srow] = bv.y;
    Bs[sc4 + 2][srow] = bv.z;
    Bs[sc4 + 3][srow] = bv.w;
    __syncthreads();
#pragma unroll
    for (int k = 0; k < 16; k++) {
      float4 a = *(const float4*)&As[k][4 * tm];
      float4 b = *(const float4*)&Bs[k][4 * tn];
      float am[4] = {a.x, a.y, a.z, a.w};
      float bb[4] = {b.x, b.y, b.z, b.w};
#pragma unroll
      for (int i = 0; i < 4; i++)
#pragma unroll
        for (int j = 0; j < 4; j++) acc[i][j] = fmaf(am[i], bb[j], acc[i][j]);
    }
    __syncthreads();
  }

#pragma unroll
  for (int i = 0; i < 4; i++) {
    int m = bm + 4 * tm + i;
#pragma unroll
    for (int j = 0; j < 4; j++) {
      int n = bn + 4 * tn + j;
      float v = acc[i][j];
      if (BIAS && ks == 0) v += bias[n];
      atomicAdd(&C[(size_t)m * N + n], v);
    }
  }
}

// ---------------------------------------------------------------------------
// Fused Fourier attention.
// qkv row (b*N+n): q at [h*64], k at [512+h*64], v at [1024+h*64].
// Grid: (16 query-chunks, H, B); block 512 threads = 8 waves, 2 queries/wave.
// Keys in 4 tiles of 64; lane=key in score phase (K from transposed LDS,
// q from LDS broadcast, num/den product trick with 4-way split chains for
// ILP); lane=dim in AV phase via per-wave A4 LDS slice (same-wave RAW).
// ---------------------------------------------------------------------------
__global__ __launch_bounds__(512, 4) void fourier_attn(
    const float* __restrict__ qkv, const float* __restrict__ paramR,
    float* __restrict__ out /* (B*N, C), head-major channels */) {
  __shared__ float KT[DH][65];    // KT[d][j] transposed key tile (padded)
  __shared__ float Vt[64][DH];    // Vt[j][d]
  __shared__ float A4[8][64][2];  // [wave][key j][query q] (stride-2: free)
  __shared__ float Qs[16][DH];    // staged queries for this block

  const int t = threadIdx.x;
  const int lane = t & 63;
  const int wv = t >> 6;  // 0..7
  const int qc = blockIdx.x;
  const int h = blockIdx.y;
  const int b = blockIdx.z;
  const float R = paramR[0];

  const float* base = qkv + (size_t)b * NN * (3 * CC) + h * DH;

  // stage the block's 16 query rows once (256 float4 slots)
  if (t < 256) {
    int r = t >> 4;          // 0..15
    int c4 = (t & 15) << 2;  // 0..60
    *(float4*)&Qs[r][c4] =
        *(const float4*)(base + (size_t)(qc * 16 + r) * (3 * CC) + c4);
  }

  float Sp[2] = {0.f, 0.f};
  float acc[2] = {0.f, 0.f};

  for (int jt = 0; jt < 4; jt++) {
    __syncthreads();  // Qs ready (first iter) / tiles free (later iters)
    // ---- stage K (transposed) and V tiles: key rows jt*64 .. jt*64+63
#pragma unroll
    for (int u0 = 0; u0 < 2; u0++) {
      int u = t + 512 * u0;    // 0..1023 float4 slots (64 rows x 16)
      int r = u >> 4;          // key row 0..63
      int c4 = (u & 15) << 2;  // dim 0..60
      const float* krow = base + (size_t)(jt * 64 + r) * (3 * CC) + CC;
      float4 kv = *(const float4*)(krow + c4);
      KT[c4 + 0][r] = kv.x;
      KT[c4 + 1][r] = kv.y;
      KT[c4 + 2][r] = kv.z;
      KT[c4 + 3][r] = kv.w;
      const float* vrow = base + (size_t)(jt * 64 + r) * (3 * CC) + 2 * CC;
      *(float4*)&Vt[r][c4] = *(const float4*)(vrow + c4);
    }
    __syncthreads();

    // ---- score phase: lane = key j = jt*64 + lane
    float kreg[DH];
#pragma unroll
    for (int d = 0; d < DH; d++) kreg[d] = KT[d][lane];  // (d+lane)%32: free

#pragma unroll
    for (int q = 0; q < 2; q++) {
      const int qi = wv * 2 + q;
      float num[4] = {1.f, 1.f, 1.f, 1.f};
      float den[4] = {1.f, 1.f, 1.f, 1.f};
#pragma unroll
      for (int d4 = 0; d4 < 16; d4++) {
        const int c = d4 >> 2;  // chain select (constant after unroll)
        float4 qv = *(const float4*)&Qs[qi][4 * d4];
        float qa[4] = {qv.x, qv.y, qv.z, qv.w};
#pragma unroll
        for (int j = 0; j < 4; j++) {
          float diff = qa[j] - kreg[4 * d4 + j];
          bool nr = fabsf(diff) < 1e-3f;  // sinc(Rd)~R, rel err <= 2e-7
          float sn = __sinf(R * diff);
          num[c] *= nr ? R : sn;
          den[c] *= nr ? 1.f : diff;
        }
      }
      float sc = ((num[0] * num[1]) * (num[2] * num[3])) /
                 ((den[0] * den[1]) * (den[2] * den[3]));
      float s2 = sc * sc;
      float a4 = s2 * s2;
      Sp[q] += a4;
      A4[wv][lane][q] = a4;
    }

    // ---- AV phase: lane = dim d; reads this wave's A4 slice (same-wave RAW)
#pragma unroll 8
    for (int j = 0; j < 64; j++) {
      float2 a4v = *(const float2*)&A4[wv][j][0];
      float vj = Vt[j][lane];
      acc[0] = fmaf(a4v.x, vj, acc[0]);
      acc[1] = fmaf(a4v.y, vj, acc[1]);
    }
  }

  // ---- finalize: reduce Sp across 64 lanes, normalize, store
#pragma unroll
  for (int q = 0; q < 2; q++) {
    float s = Sp[q];
#pragma unroll
    for (int off = 32; off > 0; off >>= 1) s += __shfl_xor(s, off, 64);
    float o = acc[q] / (s + 1e-6f);
    int n = qc * 16 + wv * 2 + q;
    out[(size_t)(b * NN + n) * CC + h * DH + lane] = o;
  }
}

// ---------------------------------------------------------------------------
extern "C" void kernel_launch(void* const* d_in, const int* in_sizes, int n_in,
                              void* d_out, int out_size, void* d_ws,
                              size_t ws_size, hipStream_t stream) {
  const float* x = (const float*)d_in[0];       // (B,N,C)
  const float* w_qkv = (const float*)d_in[1];   // (3C, C)
  const float* w_proj = (const float*)d_in[2];  // (C, C)
  const float* b_proj = (const float*)d_in[3];  // (C,)
  const float* paramR = (const float*)d_in[4];  // (1,)
  float* outp = (float*)d_out;                  // (B,N,C)

  float* qkv_ws = (float*)d_ws;                        // 1024*1536 floats
  float* attn_ws = qkv_ws + (size_t)BB * NN * 3 * CC;  // 1024*512 floats

  // zero split-K accumulation targets (graph-capturable async memset)
  (void)hipMemsetAsync(qkv_ws, 0, (size_t)BB * NN * 3 * CC * sizeof(float),
                       stream);
  (void)hipMemsetAsync(outp, 0, (size_t)BB * NN * CC * sizeof(float), stream);

  // 1) qkv = x @ w_qkv^T : M=1024, N=1536, K=512, split-K=2 -> 768 blocks
  gemm_tn_splitk<false>
      <<<dim3(3 * CC / 64, BB * NN / 64, 2), 256, 0, stream>>>(
          x, w_qkv, nullptr, qkv_ws, BB * NN, 3 * CC, CC, CC / 2);

  // 2) fused fourier attention -> attn_ws (B*N, C)
  fourier_attn<<<dim3(NN / 16, HH, BB), 512, 0, stream>>>(qkv_ws, paramR,
                                                          attn_ws);

  // 3) out = attn_ws @ w_proj^T + b_proj : M=1024, N=512, K=512, split-K=4
  gemm_tn_splitk<true>
      <<<dim3(CC / 64, BB * NN / 64, 4), 256, 0, stream>>>(
          attn_ws, w_proj, b_proj, outp, BB * NN, CC, CC, CC / 4);
}

// Round 4
// 150.307 us; speedup vs baseline: 1.9680x; 1.7242x over previous
//
#include <hip/hip_runtime.h>
#include <math.h>

// Problem constants: B=4, N=256, C=512, H=8, Dh=64
#define BB 4
#define NN 256
#define CC 512
#define HH 8
#define DH 64

typedef __attribute__((ext_vector_type(8))) short bf16x8;
typedef __attribute__((ext_vector_type(4))) float f32x4;

__device__ inline unsigned short f2bf(float f) {
  unsigned u = __float_as_uint(f);
  u += 0x7FFFu + ((u >> 16) & 1u);  // round-to-nearest-even
  return (unsigned short)(u >> 16);
}
__device__ inline float bf2f(unsigned short s) {
  return __uint_as_float((unsigned)s << 16);
}

// ---------------------------------------------------------------------------
// fp32 -> (hi, lo) bf16 split. n divisible by 1024.
// ---------------------------------------------------------------------------
__global__ __launch_bounds__(256) void cvt_hilo(
    const float* __restrict__ in, unsigned short* __restrict__ h,
    unsigned short* __restrict__ l, int n) {
  int i = (blockIdx.x * 256 + threadIdx.x) * 4;
  if (i >= n) return;
  float4 f = *(const float4*)(in + i);
  float fa[4] = {f.x, f.y, f.z, f.w};
  ushort4 hv, lv;
  unsigned short* hp = (unsigned short*)&hv;
  unsigned short* lp = (unsigned short*)&lv;
#pragma unroll
  for (int j = 0; j < 4; j++) {
    unsigned short hb = f2bf(fa[j]);
    hp[j] = hb;
    lp[j] = f2bf(fa[j] - bf2f(hb));
  }
  *(ushort4*)(h + i) = hv;
  *(ushort4*)(l + i) = lv;
}

// ---------------------------------------------------------------------------
// MFMA GEMM with bf16 hi/lo split (3 products): C = A * B^T (+bias).
// A,B row-major [M][K], [N][K] given as hi/lo bf16 pairs. C fp32 [M][N].
// Block 256 thr = 4 waves; tile 128x128; wave -> 64x64 (4x4 mfma 16x16x32).
// BK=32 (one mfma K-step). LDS rows padded to 40 shorts (16B-aligned b128,
// conflict-benign). M,N,K multiples of 128/128/32.
// ---------------------------------------------------------------------------
template <bool BIAS>
__global__ __launch_bounds__(256, 2) void gemm_mfma(
    const unsigned short* __restrict__ Ah, const unsigned short* __restrict__ Al,
    const unsigned short* __restrict__ Bh, const unsigned short* __restrict__ Bl,
    const float* __restrict__ bias, float* __restrict__ C, int M, int N,
    int K) {
  __shared__ unsigned short sAh[128][40], sAl[128][40];
  __shared__ unsigned short sBh[128][40], sBl[128][40];
  const int t = threadIdx.x;
  const int lane = t & 63;
  const int w = t >> 6;
  const int bm = blockIdx.y * 128;
  const int bn = blockIdx.x * 128;
  const int wr = (w >> 1) * 64;  // wave row offset in tile
  const int wc = (w & 1) * 64;   // wave col offset
  const int quad = lane >> 4;
  const int l16 = lane & 15;

  f32x4 acc[4][4];
#pragma unroll
  for (int i = 0; i < 4; i++)
#pragma unroll
    for (int j = 0; j < 4; j++) {
      acc[i][j][0] = 0.f;
      acc[i][j][1] = 0.f;
      acc[i][j][2] = 0.f;
      acc[i][j][3] = 0.f;
    }

  for (int k0 = 0; k0 < K; k0 += 32) {
    __syncthreads();
    // stage: 512 slots of 8 ushorts (16B) per array; 2 slots/thread
#pragma unroll
    for (int s = 0; s < 2; s++) {
      int slot = t + 256 * s;
      int r = slot >> 2;          // 0..127
      int c8 = (slot & 3) * 8;    // 0,8,16,24
      *(uint4*)&sAh[r][c8] = *(const uint4*)(Ah + (size_t)(bm + r) * K + k0 + c8);
      *(uint4*)&sAl[r][c8] = *(const uint4*)(Al + (size_t)(bm + r) * K + k0 + c8);
      *(uint4*)&sBh[r][c8] = *(const uint4*)(Bh + (size_t)(bn + r) * K + k0 + c8);
      *(uint4*)&sBl[r][c8] = *(const uint4*)(Bl + (size_t)(bn + r) * K + k0 + c8);
    }
    __syncthreads();

    bf16x8 ah[4], al[4], bh[4], bl[4];
#pragma unroll
    for (int i = 0; i < 4; i++) {
      ah[i] = *(const bf16x8*)&sAh[wr + i * 16 + l16][quad * 8];
      al[i] = *(const bf16x8*)&sAl[wr + i * 16 + l16][quad * 8];
      bh[i] = *(const bf16x8*)&sBh[wc + i * 16 + l16][quad * 8];
      bl[i] = *(const bf16x8*)&sBl[wc + i * 16 + l16][quad * 8];
    }
#pragma unroll
    for (int i = 0; i < 4; i++)
#pragma unroll
      for (int j = 0; j < 4; j++) {
        acc[i][j] = __builtin_amdgcn_mfma_f32_16x16x32_bf16(ah[i], bh[j],
                                                            acc[i][j], 0, 0, 0);
        acc[i][j] = __builtin_amdgcn_mfma_f32_16x16x32_bf16(ah[i], bl[j],
                                                            acc[i][j], 0, 0, 0);
        acc[i][j] = __builtin_amdgcn_mfma_f32_16x16x32_bf16(al[i], bh[j],
                                                            acc[i][j], 0, 0, 0);
      }
  }

  // epilogue: C/D layout col=lane&15, row=quad*4+reg (verified m89/m91)
#pragma unroll
  for (int i = 0; i < 4; i++)
#pragma unroll
    for (int j = 0; j < 4; j++) {
      int n = bn + wc + j * 16 + l16;
      float bv = BIAS ? bias[n] : 0.f;
#pragma unroll
      for (int r = 0; r < 4; r++) {
        int m = bm + wr + i * 16 + quad * 4 + r;
        C[(size_t)m * N + n] = acc[i][j][r] + bv;
      }
    }
}

// ---------------------------------------------------------------------------
// Fused Fourier attention. qkv row (b*N+n): q at [h*64], k at [512+h*64],
// v at [1024+h*64]. Grid (16,H,B); 512 thr = 8 waves, 2 queries/wave.
// Score: lane=key, K tile row-major in LDS (padded 68), b128 reads, no
// register K-cache (round-3 spill fix). sinc = sin(R*d)/(d+1e-30), exact.
// AV: lane=dim, V stored transposed for b128-over-keys reads.
// Output written directly as hi/lo bf16 for the proj MFMA GEMM.
// ---------------------------------------------------------------------------
__global__ __launch_bounds__(512, 4) void fourier_attn(
    const float* __restrict__ qkv, const float* __restrict__ paramR,
    unsigned short* __restrict__ aoh, unsigned short* __restrict__ aol) {
  __shared__ float Kt[64][68];    // Kt[key j][d], padded
  __shared__ float VtT[64][68];   // VtT[d][key j], padded
  __shared__ float Qs[16][DH];    // staged queries
  __shared__ float A4[8][64][2];  // [wave][key j][q]

  const int t = threadIdx.x;
  const int lane = t & 63;
  const int wv = t >> 6;  // 0..7
  const int qc = blockIdx.x;
  const int h = blockIdx.y;
  const int b = blockIdx.z;
  const float R = paramR[0];

  const float* base = qkv + (size_t)b * NN * (3 * CC) + h * DH;

  if (t < 256) {
    int r = t >> 4;
    int c4 = (t & 15) << 2;
    *(float4*)&Qs[r][c4] =
        *(const float4*)(base + (size_t)(qc * 16 + r) * (3 * CC) + c4);
  }

  const int qi0 = wv * 2, qi1 = wv * 2 + 1;
  float Sp[2] = {0.f, 0.f};
  float acc[2] = {0.f, 0.f};

  for (int jt = 0; jt < 4; jt++) {
    __syncthreads();
    // stage K (row-major) and V (transposed): rows jt*64..jt*64+63
#pragma unroll
    for (int u0 = 0; u0 < 2; u0++) {
      int u = t + 512 * u0;    // 0..1023 float4 slots
      int r = u >> 4;          // key row
      int c4 = (u & 15) << 2;  // dim
      const float* krow = base + (size_t)(jt * 64 + r) * (3 * CC) + CC;
      *(float4*)&Kt[r][c4] = *(const float4*)(krow + c4);
      const float* vrow = base + (size_t)(jt * 64 + r) * (3 * CC) + 2 * CC;
      float4 vv = *(const float4*)(vrow + c4);
      VtT[c4 + 0][r] = vv.x;
      VtT[c4 + 1][r] = vv.y;
      VtT[c4 + 2][r] = vv.z;
      VtT[c4 + 3][r] = vv.w;
    }
    __syncthreads();

    // ---- score phase: lane = key
    float nm[2][2] = {{1.f, 1.f}, {1.f, 1.f}};
    float dn[2][2] = {{1.f, 1.f}, {1.f, 1.f}};
#pragma unroll
    for (int d4 = 0; d4 < 16; d4++) {
      const int p = d4 & 1;
      float4 k4 = *(const float4*)&Kt[lane][4 * d4];
      float4 qa = *(const float4*)&Qs[qi0][4 * d4];
      float4 qb = *(const float4*)&Qs[qi1][4 * d4];
      float ka[4] = {k4.x, k4.y, k4.z, k4.w};
      float q0a[4] = {qa.x, qa.y, qa.z, qa.w};
      float q1a[4] = {qb.x, qb.y, qb.z, qb.w};
#pragma unroll
      for (int j = 0; j < 4; j++) {
        float d0 = q0a[j] - ka[j] + 1e-30f;
        float d1 = q1a[j] - ka[j] + 1e-30f;
        nm[0][p] *= __sinf(R * d0);
        dn[0][p] *= d0;
        nm[1][p] *= __sinf(R * d1);
        dn[1][p] *= d1;
      }
    }
#pragma unroll
    for (int q = 0; q < 2; q++) {
      float sc = (nm[q][0] * nm[q][1]) / (dn[q][0] * dn[q][1]);
      float s2 = sc * sc;
      float a4 = s2 * s2;
      Sp[q] += a4;
      A4[wv][lane][q] = a4;  // same-wave RAW with AV phase below
    }

    // ---- AV phase: lane = dim; 4 keys per iteration
#pragma unroll
    for (int j4 = 0; j4 < 16; j4++) {
      float4 v4 = *(const float4*)&VtT[lane][4 * j4];
      float4 a01 = *(const float4*)&A4[wv][4 * j4 + 0][0];  // keys j,j+1
      float4 a23 = *(const float4*)&A4[wv][4 * j4 + 2][0];  // keys j+2,j+3
      acc[0] = fmaf(a01.x, v4.x, acc[0]);
      acc[1] = fmaf(a01.y, v4.x, acc[1]);
      acc[0] = fmaf(a01.z, v4.y, acc[0]);
      acc[1] = fmaf(a01.w, v4.y, acc[1]);
      acc[0] = fmaf(a23.x, v4.z, acc[0]);
      acc[1] = fmaf(a23.y, v4.z, acc[1]);
      acc[0] = fmaf(a23.z, v4.w, acc[0]);
      acc[1] = fmaf(a23.w, v4.w, acc[1]);
    }
  }

  // ---- finalize: reduce Sp, normalize, store hi/lo bf16
#pragma unroll
  for (int q = 0; q < 2; q++) {
    float s = Sp[q];
#pragma unroll
    for (int off = 32; off > 0; off >>= 1) s += __shfl_xor(s, off, 64);
    float o = acc[q] / (s + 1e-6f);
    int n = qc * 16 + wv * 2 + q;
    size_t idx = (size_t)(b * NN + n) * CC + h * DH + lane;
    unsigned short oh = f2bf(o);
    aoh[idx] = oh;
    aol[idx] = f2bf(o - bf2f(oh));
  }
}

// ---------------------------------------------------------------------------
extern "C" void kernel_launch(void* const* d_in, const int* in_sizes, int n_in,
                              void* d_out, int out_size, void* d_ws,
                              size_t ws_size, hipStream_t stream) {
  const float* x = (const float*)d_in[0];       // (B,N,C)
  const float* w_qkv = (const float*)d_in[1];   // (3C, C)
  const float* w_proj = (const float*)d_in[2];  // (C, C)
  const float* b_proj = (const float*)d_in[3];  // (C,)
  const float* paramR = (const float*)d_in[4];  // (1,)
  float* outp = (float*)d_out;                  // (B,N,C)

  const int nX = BB * NN * CC;        // 524288
  const int nWq = 3 * CC * CC;        // 786432
  const int nWp = CC * CC;            // 262144

  // ws layout (all 16B-aligned)
  unsigned short* xh = (unsigned short*)d_ws;
  unsigned short* xl = xh + nX;
  unsigned short* wqh = xl + nX;
  unsigned short* wql = wqh + nWq;
  unsigned short* wph = wql + nWq;
  unsigned short* wpl = wph + nWp;
  unsigned short* aoh = wpl + nWp;
  unsigned short* aol = aoh + nX;
  float* qkv_ws = (float*)(aol + nX);  // 1024*1536 fp32

  // 1) hi/lo conversions
  cvt_hilo<<<nX / 1024, 256, 0, stream>>>(x, xh, xl, nX);
  cvt_hilo<<<nWq / 1024, 256, 0, stream>>>(w_qkv, wqh, wql, nWq);
  cvt_hilo<<<nWp / 1024, 256, 0, stream>>>(w_proj, wph, wpl, nWp);

  // 2) qkv = x @ w_qkv^T : M=1024, N=1536, K=512
  gemm_mfma<false><<<dim3(3 * CC / 128, BB * NN / 128), 256, 0, stream>>>(
      xh, xl, wqh, wql, nullptr, qkv_ws, BB * NN, 3 * CC, CC);

  // 3) fused fourier attention -> hi/lo bf16 (B*N, C)
  fourier_attn<<<dim3(NN / 16, HH, BB), 512, 0, stream>>>(qkv_ws, paramR, aoh,
                                                          aol);

  // 4) out = attn @ w_proj^T + b_proj : M=1024, N=512, K=512
  gemm_mfma<true><<<dim3(CC / 128, BB * NN / 128), 256, 0, stream>>>(
      aoh, aol, wph, wpl, b_proj, outp, BB * NN, CC, CC);
}